// Round 6
// baseline (1292.692 us; speedup 1.0000x reference)
//
#include <hip/hip_runtime.h>

#define T_STEPS 2000
#define BATCH   256
#define F_IN    80
#define HDIM    64

template<int N> struct IC { static constexpr int v = N; };

typedef _Float16 h2 __attribute__((ext_vector_type(2)));
typedef _Float16 h8 __attribute__((ext_vector_type(8)));

union U8 { h8 v; h2 p[4]; };

// ---- fast transcendentals (fp32; logits threshold 1.77e-2) ----
__device__ __forceinline__ float sigm_f(float v) {
    float e = __expf(-v);
    return __builtin_amdgcn_rcpf(1.f + e);
}
__device__ __forceinline__ float tanh_f(float v) {
    v = fminf(fmaxf(v, -15.f), 15.f);
    float e = __expf(-2.f * v);
    return (1.f - e) * __builtin_amdgcn_rcpf(1.f + e);
}
// LDS-only barrier: drains LDS ops (lgkmcnt=0) but leaves global loads in
// flight (vmcnt=63). Proven safe in rounds 3-4.
__device__ __forceinline__ void barrier_lds() {
    __builtin_amdgcn_s_waitcnt(0xC07F);   // vmcnt=63, expcnt=7, lgkmcnt=0
    __builtin_amdgcn_s_barrier();
}
__device__ __forceinline__ h2 mk2(float a, float b) {
    h2 r; r.x = (_Float16)a; r.y = (_Float16)b; return r;
}
// combine a packed-fp16 accumulator into fp32
__device__ __forceinline__ float hsum(h2 a) { return (float)a.x + (float)a.y; }

// ---------------------------------------------------------------------------
// gx GEMM: gx[r,c] = bias(c) + Wih0[c,:] . x[r,:], fp16 out, biases folded.
// v_pk_fma_f16 dots (full-rate, 4 accumulators/gate). Staging ds_write moved
// BEFORE the dot block so the next row's reads never wait on a fresh write.
// ---------------------------------------------------------------------------
__global__ __launch_bounds__(64, 2)
void gx_gemm(const float* __restrict__ x,        // [B*T, 80] fp32
             const float* __restrict__ Wih0,     // [192, 80] fp32
             const float* __restrict__ bih0,
             const float* __restrict__ bhh0,
             _Float16* __restrict__ gxp)         // [B*T, 192] fp16
{
    const int j = threadIdx.x;                   // 0..63
    const long total = (long)BATCH * T_STEPS;
    const long per   = total / gridDim.x;        // 250
    const long r0    = (long)blockIdx.x * per;
    const long r1    = r0 + per;

    h2 wr[40], wz[40], wn[40];
    {
        const float4* a4 = (const float4*)(Wih0 + (size_t)j * F_IN);
        const float4* b4 = (const float4*)(Wih0 + (size_t)(64 + j) * F_IN);
        const float4* c4 = (const float4*)(Wih0 + (size_t)(128 + j) * F_IN);
        #pragma unroll
        for (int k = 0; k < 20; ++k) {
            float4 va = a4[k], vb = b4[k], vc = c4[k];
            wr[2*k] = mk2(va.x, va.y); wr[2*k+1] = mk2(va.z, va.w);
            wz[2*k] = mk2(vb.x, vb.y); wz[2*k+1] = mk2(vb.z, vb.w);
            wn[2*k] = mk2(vc.x, vc.y); wn[2*k+1] = mk2(vc.z, vc.w);
        }
    }
    const float br = bih0[j]       + bhh0[j];
    const float bz = bih0[64 + j]  + bhh0[64 + j];
    const float bn = bih0[128 + j];

    __shared__ __align__(16) _Float16 xs[2][80];
    const h2 z2 = mk2(0.f, 0.f);

    if (j < 40) {
        float2 v = ((const float2*)(x + r0 * F_IN))[j];
        *(h2*)&xs[0][2 * j] = mk2(v.x, v.y);
    }
    float2 vn = make_float2(0.f, 0.f);
    if (j < 40 && r0 + 1 < r1) vn = ((const float2*)(x + (r0 + 1) * F_IN))[j];

    for (long r = r0; r < r1; ++r) {
        const int cur = (int)(r - r0) & 1;
        // distance-2 prefetch (in flight across this row's compute)
        float2 v2 = make_float2(0.f, 0.f);
        if (j < 40 && r + 2 < r1) v2 = ((const float2*)(x + (r + 2) * F_IN))[j];

        U8 xv[10];
        #pragma unroll
        for (int q = 0; q < 10; ++q) xv[q].v = ((const h8*)xs[cur])[q];

        // stage row r+1 NOW (vn loaded a full row ago; write completes while
        // the dots below run, so next row's reads never stall on it)
        if (j < 40 && r + 1 < r1) *(h2*)&xs[cur ^ 1][2 * j] = mk2(vn.x, vn.y);
        vn = v2;

        h2 aR[4] = {z2, z2, z2, z2}, aZ[4] = {z2, z2, z2, z2}, aN[4] = {z2, z2, z2, z2};
        #pragma unroll
        for (int q = 0; q < 10; ++q)
            #pragma unroll
            for (int p = 0; p < 4; ++p) {
                aR[p] = wr[4*q+p] * xv[q].p[p] + aR[p];
                aZ[p] = wz[4*q+p] * xv[q].p[p] + aZ[p];
                aN[p] = wn[4*q+p] * xv[q].p[p] + aN[p];
            }
        float ar = br + hsum((aR[0] + aR[1]) + (aR[2] + aR[3]));
        float az = bz + hsum((aZ[0] + aZ[1]) + (aZ[2] + aZ[3]));
        float an = bn + hsum((aN[0] + aN[1]) + (aN[2] + aN[3]));

        _Float16* g = gxp + r * 192;
        g[j]       = (_Float16)ar;
        g[64 + j]  = (_Float16)az;
        g[128 + j] = (_Float16)an;
    }
}

// ---------------------------------------------------------------------------
// Fused 2-layer GRU scan — round-4 proven control flow (3 waves, 1 barrier
// per step, lgkmcnt(0)-drain barriers), with:
//   * all dots as v_pk_fma_f16 (full-rate; 2 fp16 accumulators per gate)
//   * all LDS reads at TOP of body (post-barrier) so the barrier drain only
//     covers the tiny writes; read latency hides under gx-cvt/addr VALU.
//   w0 @ step i : h0[i]   = GRU(gx[i], Whh0 . h0[i-1])
//   w1 @ step i : px[i-1] = bias + Wih1 . h0[i-1]
//   w2 @ step i : h1[i-2] = GRU(px[i-2], Whh1 . h1[i-3])
// ---------------------------------------------------------------------------
__global__ __launch_bounds__(192, 1)
void gru_scan(const _Float16* __restrict__ gx,   // [B*T, 192] fp16 (bias-folded)
              const float* __restrict__ hin,     // [2,B,H]
              const float* __restrict__ Whh0,    // [192,64]
              const float* __restrict__ bhh0,
              const float* __restrict__ Wih1,    // [192,64]
              const float* __restrict__ Whh1,    // [192,64]
              const float* __restrict__ bih1, const float* __restrict__ bhh1,
              float* __restrict__ out_hidden)    // [2,B,H] region of d_out
{
    const int b = blockIdx.x;
    const int j = threadIdx.x & 63;
    const int w = threadIdx.x >> 6;

    __shared__ __align__(16) _Float16 h0r[4][64];   // ring: slot i&3 = h0[i]
    __shared__ __align__(16) _Float16 h1r[2][64];   // ping-pong: slot t&1 = h1[t]
    __shared__ __align__(16) float    pxs[2][3][64];// ping-pong: slot t&1 = px[t]

    const h2 z2 = mk2(0.f, 0.f);

    if (w == 0) {
        // ---- wave 0: layer-0 recurrence ----
        h2 whr[32], whz[32], whn[32];
        {
            const float4* a4 = (const float4*)(Whh0 + (size_t)j * HDIM);
            const float4* b4 = (const float4*)(Whh0 + (size_t)(64 + j) * HDIM);
            const float4* c4 = (const float4*)(Whh0 + (size_t)(128 + j) * HDIM);
            #pragma unroll
            for (int k = 0; k < 16; ++k) {
                float4 va = a4[k], vb = b4[k], vc = c4[k];
                whr[2*k]=mk2(va.x,va.y); whr[2*k+1]=mk2(va.z,va.w);
                whz[2*k]=mk2(vb.x,vb.y); whz[2*k+1]=mk2(vb.z,vb.w);
                whn[2*k]=mk2(vc.x,vc.y); whn[2*k+1]=mk2(vc.z,vc.w);
            }
        }
        const float bn0h = bhh0[128 + j];
        float hreg = hin[b * HDIM + j];
        h0r[3][j] = (_Float16)hreg;                 // h0[-1] at slot 3

        const _Float16* gbase = gx + (size_t)b * T_STEPS * 192;
        _Float16 grf[2], gzf[2], gnf[2];            // depth-2 gx prefetch
        grf[0] = gbase[j];       gzf[0] = gbase[64 + j];       gnf[0] = gbase[128 + j];
        grf[1] = gbase[192 + j]; gzf[1] = gbase[192 + 64 + j]; gnf[1] = gbase[192 + 128 + j];

        __syncthreads();

        auto stepL0 = [&](int i, auto c3) {
            constexpr int I3 = decltype(c3)::v;     // i&3
            constexpr int IP = I3 & 1;
            constexpr int IR = (I3 + 3) & 3;        // (i-1)&3
            // top-of-body reads: h0[i-1] (8 x ds_read_b128, issued first)
            U8 hA[4], hB[4];
            #pragma unroll
            for (int q = 0; q < 4; ++q) hA[q].v = ((const h8*)h0r[IR])[q];
            #pragma unroll
            for (int q = 0; q < 4; ++q) hB[q].v = ((const h8*)h0r[IR])[4 + q];
            // gx cvt + next prefetch: VALU/VMEM that hides the ds_read latency
            float gr = (float)grf[IP];
            float gz = (float)gzf[IP];
            float gn = (float)gnf[IP];
            const int ipf = (i + 2 < T_STEPS) ? (i + 2) : (T_STEPS - 1);  // in-bounds
            const _Float16* gnx = gbase + (size_t)ipf * 192 + j;
            grf[IP] = gnx[0]; gzf[IP] = gnx[64]; gnf[IP] = gnx[128];

            h2 aR[2] = {z2, z2}, aZ[2] = {z2, z2}, aN[2] = {z2, z2};
            #pragma unroll
            for (int q = 0; q < 4; ++q)
                #pragma unroll
                for (int p = 0; p < 4; ++p) {
                    aR[p&1] = whr[4*q+p] * hA[q].p[p] + aR[p&1];
                    aZ[p&1] = whz[4*q+p] * hA[q].p[p] + aZ[p&1];
                    aN[p&1] = whn[4*q+p] * hA[q].p[p] + aN[p&1];
                }
            #pragma unroll
            for (int q = 0; q < 4; ++q)
                #pragma unroll
                for (int p = 0; p < 4; ++p) {
                    aR[p&1] = whr[16+4*q+p] * hB[q].p[p] + aR[p&1];
                    aZ[p&1] = whz[16+4*q+p] * hB[q].p[p] + aZ[p&1];
                    aN[p&1] = whn[16+4*q+p] * hB[q].p[p] + aN[p&1];
                }
            float r = sigm_f(gr + hsum(aR[0] + aR[1]));
            float z = sigm_f(gz + hsum(aZ[0] + aZ[1]));
            float anh = bn0h + hsum(aN[0] + aN[1]);
            float n = tanh_f(gn + r * anh);
            hreg = (1.f - z) * n + z * hreg;
            h0r[I3][j] = (_Float16)hreg;            // one ds_write_b16
            barrier_lds();                          // drain = write only (cheap)
        };

        for (int ii = 0; ii < T_STEPS / 4; ++ii) {
            const int i = 4 * ii;
            stepL0(i + 0, IC<0>{}); stepL0(i + 1, IC<1>{});
            stepL0(i + 2, IC<2>{}); stepL0(i + 3, IC<3>{});
        }
        barrier_lds();                              // epilogue (match w1/w2)
        out_hidden[b * HDIM + j] = hreg;            // h0[T-1]
    } else if (w == 1) {
        // ---- wave 1: layer-1 x-side projections ----
        h2 xr1[32], xz1[32], xn1[32];
        {
            const float4* a4 = (const float4*)(Wih1 + (size_t)j * HDIM);
            const float4* b4 = (const float4*)(Wih1 + (size_t)(64 + j) * HDIM);
            const float4* c4 = (const float4*)(Wih1 + (size_t)(128 + j) * HDIM);
            #pragma unroll
            for (int k = 0; k < 16; ++k) {
                float4 va = a4[k], vb = b4[k], vc = c4[k];
                xr1[2*k]=mk2(va.x,va.y); xr1[2*k+1]=mk2(va.z,va.w);
                xz1[2*k]=mk2(vb.x,vb.y); xz1[2*k+1]=mk2(vb.z,vb.w);
                xn1[2*k]=mk2(vc.x,vc.y); xn1[2*k+1]=mk2(vc.z,vc.w);
            }
        }
        const float brm = bih1[j] + bhh1[j];
        const float bzm = bih1[64 + j] + bhh1[64 + j];
        const float bnx = bih1[128 + j];

        __syncthreads();

        auto stepW1 = [&](auto c3) {   // at step i: px[i-1] = bias + Wih1.h0[i-1]
            constexpr int I3 = decltype(c3)::v;     // i&3
            constexpr int IR = (I3 + 3) & 3;        // (i-1)&3
            constexpr int PS = (I3 + 1) & 1;        // (i-1)&1
            U8 hA[4], hB[4];
            #pragma unroll
            for (int q = 0; q < 4; ++q) hA[q].v = ((const h8*)h0r[IR])[q];
            #pragma unroll
            for (int q = 0; q < 4; ++q) hB[q].v = ((const h8*)h0r[IR])[4 + q];
            h2 aR[2] = {z2, z2}, aZ[2] = {z2, z2}, aN[2] = {z2, z2};
            #pragma unroll
            for (int q = 0; q < 4; ++q)
                #pragma unroll
                for (int p = 0; p < 4; ++p) {
                    aR[p&1] = xr1[4*q+p] * hA[q].p[p] + aR[p&1];
                    aZ[p&1] = xz1[4*q+p] * hA[q].p[p] + aZ[p&1];
                    aN[p&1] = xn1[4*q+p] * hA[q].p[p] + aN[p&1];
                }
            #pragma unroll
            for (int q = 0; q < 4; ++q)
                #pragma unroll
                for (int p = 0; p < 4; ++p) {
                    aR[p&1] = xr1[16+4*q+p] * hB[q].p[p] + aR[p&1];
                    aZ[p&1] = xz1[16+4*q+p] * hB[q].p[p] + aZ[p&1];
                    aN[p&1] = xn1[16+4*q+p] * hB[q].p[p] + aN[p&1];
                }
            pxs[PS][0][j] = brm + hsum(aR[0] + aR[1]);   // 3 ds_write_b32
            pxs[PS][1][j] = bzm + hsum(aZ[0] + aZ[1]);
            pxs[PS][2][j] = bnx + hsum(aN[0] + aN[1]);
            barrier_lds();
        };

        barrier_lds();                              // i = 0 (idle)
        stepW1(IC<1>{}); stepW1(IC<2>{}); stepW1(IC<3>{});
        for (int ii = 1; ii < T_STEPS / 4; ++ii) {
            stepW1(IC<0>{}); stepW1(IC<1>{});
            stepW1(IC<2>{}); stepW1(IC<3>{});
        }
        stepW1(IC<0>{});                            // epilogue: px[T-1]
    } else {
        // ---- wave 2: layer-1 recurrence + gates ----
        h2 hr1[32], hz1[32], hn1[32];
        {
            const float4* a4 = (const float4*)(Whh1 + (size_t)j * HDIM);
            const float4* b4 = (const float4*)(Whh1 + (size_t)(64 + j) * HDIM);
            const float4* c4 = (const float4*)(Whh1 + (size_t)(128 + j) * HDIM);
            #pragma unroll
            for (int k = 0; k < 16; ++k) {
                float4 va = a4[k], vb = b4[k], vc = c4[k];
                hr1[2*k]=mk2(va.x,va.y); hr1[2*k+1]=mk2(va.z,va.w);
                hz1[2*k]=mk2(vb.x,vb.y); hz1[2*k+1]=mk2(vb.z,vb.w);
                hn1[2*k]=mk2(vc.x,vc.y); hn1[2*k+1]=mk2(vc.z,vc.w);
            }
        }
        const float bnh = bhh1[128 + j];
        float hreg = hin[BATCH * HDIM + b * HDIM + j];
        h1r[1][j] = (_Float16)hreg;                 // h1[-1] at slot 1

        __syncthreads();

        auto stepW2 = [&](auto c3) {   // at step i: t = i-2
            constexpr int I3 = decltype(c3)::v;     // i&3
            constexpr int IP = I3 & 1;              // t&1 == i&1
            constexpr int IU = IP ^ 1;              // (i-3)&1 = slot of h1[i-3]
            // top-of-body reads: px[i-2] + h1[i-3]
            const float pr = pxs[IP][0][j];
            const float pz = pxs[IP][1][j];
            const float pn = pxs[IP][2][j];
            U8 hA[4], hB[4];
            #pragma unroll
            for (int q = 0; q < 4; ++q) hA[q].v = ((const h8*)h1r[IU])[q];
            #pragma unroll
            for (int q = 0; q < 4; ++q) hB[q].v = ((const h8*)h1r[IU])[4 + q];
            h2 aR[2] = {z2, z2}, aZ[2] = {z2, z2}, aN[2] = {z2, z2};
            #pragma unroll
            for (int q = 0; q < 4; ++q)
                #pragma unroll
                for (int p = 0; p < 4; ++p) {
                    aR[p&1] = hr1[4*q+p] * hA[q].p[p] + aR[p&1];
                    aZ[p&1] = hz1[4*q+p] * hA[q].p[p] + aZ[p&1];
                    aN[p&1] = hn1[4*q+p] * hA[q].p[p] + aN[p&1];
                }
            #pragma unroll
            for (int q = 0; q < 4; ++q)
                #pragma unroll
                for (int p = 0; p < 4; ++p) {
                    aR[p&1] = hr1[16+4*q+p] * hB[q].p[p] + aR[p&1];
                    aZ[p&1] = hz1[16+4*q+p] * hB[q].p[p] + aZ[p&1];
                    aN[p&1] = hn1[16+4*q+p] * hB[q].p[p] + aN[p&1];
                }
            float r = sigm_f(pr + hsum(aR[0] + aR[1]));
            float z = sigm_f(pz + hsum(aZ[0] + aZ[1]));
            float anh = bnh + hsum(aN[0] + aN[1]);
            float n = tanh_f(pn + r * anh);
            hreg = (1.f - z) * n + z * hreg;
            h1r[IP][j] = (_Float16)hreg;            // h1[i-2]
            barrier_lds();
        };

        barrier_lds(); barrier_lds();               // i = 0, 1 (idle)
        stepW2(IC<2>{}); stepW2(IC<3>{});
        for (int ii = 1; ii < T_STEPS / 4; ++ii) {
            stepW2(IC<0>{}); stepW2(IC<1>{});
            stepW2(IC<2>{}); stepW2(IC<3>{});
        }
        stepW2(IC<0>{});                            // epilogue: t = T-2
        {   // tail: t = T-1 (no barrier; px[T-1] in pxs[1], h1[T-2] in h1r[0])
            const float pr = pxs[1][0][j];
            const float pz = pxs[1][1][j];
            const float pn = pxs[1][2][j];
            U8 hA[4], hB[4];
            #pragma unroll
            for (int q = 0; q < 4; ++q) hA[q].v = ((const h8*)h1r[0])[q];
            #pragma unroll
            for (int q = 0; q < 4; ++q) hB[q].v = ((const h8*)h1r[0])[4 + q];
            h2 aR[2] = {z2, z2}, aZ[2] = {z2, z2}, aN[2] = {z2, z2};
            #pragma unroll
            for (int q = 0; q < 4; ++q)
                #pragma unroll
                for (int p = 0; p < 4; ++p) {
                    aR[p&1] = hr1[4*q+p] * hA[q].p[p] + aR[p&1];
                    aZ[p&1] = hz1[4*q+p] * hA[q].p[p] + aZ[p&1];
                    aN[p&1] = hn1[4*q+p] * hA[q].p[p] + aN[p&1];
                }
            #pragma unroll
            for (int q = 0; q < 4; ++q)
                #pragma unroll
                for (int p = 0; p < 4; ++p) {
                    aR[p&1] = hr1[16+4*q+p] * hB[q].p[p] + aR[p&1];
                    aZ[p&1] = hz1[16+4*q+p] * hB[q].p[p] + aZ[p&1];
                    aN[p&1] = hn1[16+4*q+p] * hB[q].p[p] + aN[p&1];
                }
            float r = sigm_f(pr + hsum(aR[0] + aR[1]));
            float z = sigm_f(pz + hsum(aZ[0] + aZ[1]));
            float anh = bnh + hsum(aN[0] + aN[1]);
            float n = tanh_f(pn + r * anh);
            hreg = (1.f - z) * n + z * hreg;
        }
        out_hidden[BATCH * HDIM + b * HDIM + j] = hreg;   // h1[T-1]
    }
}

// logits[b][o] = b_fc[o] + sum_j relu(h1T[b][j]) * W_fc[o][j]
__global__ void fc_kernel(const float* __restrict__ hidden,   // [2,B,H] region
                          const float* __restrict__ Wfc,      // [29,64]
                          const float* __restrict__ bfc,      // [29]
                          float* __restrict__ logits)         // [B,29]
{
    const int b = blockIdx.x;
    const int o = threadIdx.x;
    if (o < 29) {
        const float* hb = hidden + BATCH * HDIM + b * HDIM;   // h1T
        float acc = bfc[o];
        #pragma unroll
        for (int j = 0; j < HDIM; ++j)
            acc += fmaxf(hb[j], 0.f) * Wfc[o * HDIM + j];
        logits[b * 29 + o] = acc;
    }
}

extern "C" void kernel_launch(void* const* d_in, const int* in_sizes, int n_in,
                              void* d_out, int out_size, void* d_ws, size_t ws_size,
                              hipStream_t stream) {
    const float* x    = (const float*)d_in[0];
    const float* h    = (const float*)d_in[1];
    const float* Wih0 = (const float*)d_in[2];
    const float* Whh0 = (const float*)d_in[3];
    const float* bih0 = (const float*)d_in[4];
    const float* bhh0 = (const float*)d_in[5];
    const float* Wih1 = (const float*)d_in[6];
    const float* Whh1 = (const float*)d_in[7];
    const float* bih1 = (const float*)d_in[8];
    const float* bhh1 = (const float*)d_in[9];
    const float* Wfc  = (const float*)d_in[10];
    const float* bfc  = (const float*)d_in[11];

    float* out    = (float*)d_out;
    float* logits = out;                      // [256,29]
    float* hidden = out + BATCH * 29;         // [2,256,64]

    // Workspace: gx fp16 [B*T][192] = 196,608,000 B. All accesses in-bounds
    // (scan-side prefetch row clamped to T_STEPS-1).
    _Float16* gxp = (_Float16*)d_ws;

    gx_gemm<<<2048, 64, 0, stream>>>(x, Wih0, bih0, bhh0, gxp);
    gru_scan<<<BATCH, 192, 0, stream>>>(
        gxp, h, Whh0, bhh0, Wih1, Whh1, bih1, bhh1, hidden);
    fc_kernel<<<BATCH, 64, 0, stream>>>(hidden, Wfc, bfc, logits);
}

// Round 7
// 1202.762 us; speedup vs baseline: 1.0748x; 1.0748x over previous
//
#include <hip/hip_runtime.h>

#define T_STEPS 2000
#define BATCH   256
#define F_IN    80
#define HDIM    64

template<int N> struct IC { static constexpr int v = N; };

typedef _Float16 h2 __attribute__((ext_vector_type(2)));
typedef _Float16 h8 __attribute__((ext_vector_type(8)));

union U8 { h8 v; h2 p[4]; };

// ---- fast transcendentals (fp32; logits threshold 1.77e-2) ----
__device__ __forceinline__ float sigm_f(float v) {
    float e = __expf(-v);
    return __builtin_amdgcn_rcpf(1.f + e);
}
__device__ __forceinline__ float tanh_f(float v) {
    v = fminf(fmaxf(v, -15.f), 15.f);
    float e = __expf(-2.f * v);
    return (1.f - e) * __builtin_amdgcn_rcpf(1.f + e);
}
// LDS-only barrier: drains LDS ops (lgkmcnt=0) but leaves global loads in
// flight (vmcnt=63). Proven safe in rounds 3/4/6.
__device__ __forceinline__ void barrier_lds() {
    __builtin_amdgcn_s_waitcnt(0xC07F);   // vmcnt=63, expcnt=7, lgkmcnt=0
    __builtin_amdgcn_s_barrier();
}
// v_dot2_f32_f16: 2 fp16 MACs, fp32 accumulate (round-4 proven numerics).
__device__ __forceinline__ float fdot2(h2 a, h2 b, float c) {
    return __builtin_amdgcn_fdot2(a, b, c, false);
}
__device__ __forceinline__ h2 mk2(float a, float b) {
    h2 r; r.x = (_Float16)a; r.y = (_Float16)b; return r;
}

// 96 dot2 = 3 gates x 64-K dot products, fp32 accumulation.
#define DOT96(WR, WZ, WN, HA, HB, AR, AZ, AN)                 \
    {                                                          \
        _Pragma("unroll")                                      \
        for (int q = 0; q < 4; ++q) {                          \
            _Pragma("unroll")                                  \
            for (int pp = 0; pp < 4; ++pp) {                   \
                AR = fdot2(WR[4*q+pp], HA[q].p[pp], AR);       \
                AZ = fdot2(WZ[4*q+pp], HA[q].p[pp], AZ);       \
                AN = fdot2(WN[4*q+pp], HA[q].p[pp], AN);       \
            }                                                  \
        }                                                      \
        _Pragma("unroll")                                      \
        for (int q = 0; q < 4; ++q) {                          \
            _Pragma("unroll")                                  \
            for (int pp = 0; pp < 4; ++pp) {                   \
                AR = fdot2(WR[16+4*q+pp], HB[q].p[pp], AR);    \
                AZ = fdot2(WZ[16+4*q+pp], HB[q].p[pp], AZ);    \
                AN = fdot2(WN[16+4*q+pp], HB[q].p[pp], AN);    \
            }                                                  \
        }                                                      \
    }

// ---------------------------------------------------------------------------
// gx GEMM: gx[r,c] = bias(c) + Wih0[c,:] . x[r,:], fp16 out, biases folded.
// 4096 blocks x 1 wave x 125 rows (TLP doubled vs round 4 to hide HBM latency;
// weights stay register-resident). Early LDS staging write (round-6 proven).
// ---------------------------------------------------------------------------
__global__ __launch_bounds__(64, 2)
void gx_gemm(const float* __restrict__ x,        // [B*T, 80] fp32
             const float* __restrict__ Wih0,     // [192, 80] fp32
             const float* __restrict__ bih0,
             const float* __restrict__ bhh0,
             _Float16* __restrict__ gxp)         // [B*T, 192] fp16
{
    const int j = threadIdx.x;                   // 0..63
    const long total = (long)BATCH * T_STEPS;
    const long per   = total / gridDim.x;        // 125
    const long r0    = (long)blockIdx.x * per;
    const long r1    = r0 + per;

    h2 wr[40], wz[40], wn[40];
    {
        const float4* a4 = (const float4*)(Wih0 + (size_t)j * F_IN);
        const float4* b4 = (const float4*)(Wih0 + (size_t)(64 + j) * F_IN);
        const float4* c4 = (const float4*)(Wih0 + (size_t)(128 + j) * F_IN);
        #pragma unroll
        for (int k = 0; k < 20; ++k) {
            float4 va = a4[k], vb = b4[k], vc = c4[k];
            wr[2*k] = mk2(va.x, va.y); wr[2*k+1] = mk2(va.z, va.w);
            wz[2*k] = mk2(vb.x, vb.y); wz[2*k+1] = mk2(vb.z, vb.w);
            wn[2*k] = mk2(vc.x, vc.y); wn[2*k+1] = mk2(vc.z, vc.w);
        }
    }
    const float br = bih0[j]       + bhh0[j];
    const float bz = bih0[64 + j]  + bhh0[64 + j];
    const float bn = bih0[128 + j];

    __shared__ __align__(16) _Float16 xs[2][80];

    if (j < 40) {
        float2 v = ((const float2*)(x + r0 * F_IN))[j];
        *(h2*)&xs[0][2 * j] = mk2(v.x, v.y);
    }
    float2 vn = make_float2(0.f, 0.f);
    if (j < 40 && r0 + 1 < r1) vn = ((const float2*)(x + (r0 + 1) * F_IN))[j];

    for (long r = r0; r < r1; ++r) {
        const int cur = (int)(r - r0) & 1;
        // distance-2 prefetch (in flight across this row's compute)
        float2 v2 = make_float2(0.f, 0.f);
        if (j < 40 && r + 2 < r1) v2 = ((const float2*)(x + (r + 2) * F_IN))[j];

        U8 xv[10];
        #pragma unroll
        for (int q = 0; q < 10; ++q) xv[q].v = ((const h8*)xs[cur])[q];

        // stage row r+1 now (vn loaded a full row ago; write completes under dots)
        if (j < 40 && r + 1 < r1) *(h2*)&xs[cur ^ 1][2 * j] = mk2(vn.x, vn.y);
        vn = v2;

        float ar = br, az = bz, an = bn;
        #pragma unroll
        for (int q = 0; q < 10; ++q)
            #pragma unroll
            for (int pp = 0; pp < 4; ++pp) {
                ar = fdot2(wr[4*q+pp], xv[q].p[pp], ar);
                az = fdot2(wz[4*q+pp], xv[q].p[pp], az);
                an = fdot2(wn[4*q+pp], xv[q].p[pp], an);
            }
        _Float16* g = gxp + r * 192;
        g[j]       = (_Float16)ar;
        g[64 + j]  = (_Float16)az;
        g[128 + j] = (_Float16)an;
    }
}

// ---------------------------------------------------------------------------
// Fused 2-layer GRU scan — SUPERSTEP schedule: one barrier per TWO timesteps.
// 192 threads = 3 waves. Superstep S (S = 0..1001):
//   w0 (S<1000)      : h0[2S], h0[2S+1]       (2nd sub-step reads own write,
//                                              intra-wave DS order, no sync)
//   w1 (1<=S<=1000)  : px[2S-2], px[2S-1] = bias + Wih1 . h0[.]  (lag 2)
//   w2 (S>=2)        : h1[2S-4], h1[2S-3]                         (lag 4)
// Cross-wave production->consumption distance is always >= 1 superstep, so
// one barrier per superstep suffices. Rings: h0[4], px[4] (slot-disjoint
// per superstep, verified mod-4), h1 ping-pong (w2-private). All slot
// indices compile-time via S-parity unrolled bodies.
// ---------------------------------------------------------------------------
__global__ __launch_bounds__(192, 1)
void gru_scan(const _Float16* __restrict__ gx,   // [B*T, 192] fp16 (bias-folded)
              const float* __restrict__ hin,     // [2,B,H]
              const float* __restrict__ Whh0,    // [192,64]
              const float* __restrict__ bhh0,
              const float* __restrict__ Wih1,    // [192,64]
              const float* __restrict__ Whh1,    // [192,64]
              const float* __restrict__ bih1, const float* __restrict__ bhh1,
              float* __restrict__ out_hidden)    // [2,B,H] region of d_out
{
    const int b = blockIdx.x;
    const int j = threadIdx.x & 63;
    const int w = threadIdx.x >> 6;

    __shared__ __align__(16) _Float16 h0r[4][64];   // ring: slot t&3 = h0[t]
    __shared__ __align__(16) _Float16 h1r[2][64];   // slot t&1 = h1[t] (w2 only)
    __shared__ __align__(16) float    pxs[4][3][64];// ring: slot t&3 = px[t]

    if (w == 0) {
        // ---- wave 0: layer-0 recurrence, 2 steps per superstep ----
        h2 whr[32], whz[32], whn[32];
        {
            const float4* a4 = (const float4*)(Whh0 + (size_t)j * HDIM);
            const float4* b4 = (const float4*)(Whh0 + (size_t)(64 + j) * HDIM);
            const float4* c4 = (const float4*)(Whh0 + (size_t)(128 + j) * HDIM);
            #pragma unroll
            for (int k = 0; k < 16; ++k) {
                float4 va = a4[k], vb = b4[k], vc = c4[k];
                whr[2*k]=mk2(va.x,va.y); whr[2*k+1]=mk2(va.z,va.w);
                whz[2*k]=mk2(vb.x,vb.y); whz[2*k+1]=mk2(vb.z,vb.w);
                whn[2*k]=mk2(vc.x,vc.y); whn[2*k+1]=mk2(vc.z,vc.w);
            }
        }
        const float bn0h = bhh0[128 + j];
        float hreg = hin[b * HDIM + j];
        h0r[3][j] = (_Float16)hreg;                 // h0[-1] at slot 3

        const _Float16* gbase = gx + (size_t)b * T_STEPS * 192;
        _Float16 gxr[4], gxz[4], gxn[4];            // gx regs, set = t&3
        #pragma unroll
        for (int t = 0; t < 4; ++t) {
            gxr[t] = gbase[t * 192 + j];
            gxz[t] = gbase[t * 192 + 64 + j];
            gxn[t] = gbase[t * 192 + 128 + j];
        }

        __syncthreads();

        U8 hA0[4], hB0[4];                          // sub0 source (pre-read)
        #pragma unroll
        for (int q = 0; q < 4; ++q) hA0[q].v = ((const h8*)h0r[3])[q];
        #pragma unroll
        for (int q = 0; q < 4; ++q) hB0[q].v = ((const h8*)h0r[3])[4 + q];

        auto superW0 = [&](int S, auto cA) {
            constexpr int A = decltype(cA)::v;      // (2S)&3 : 0 (S even) / 2 (S odd)
            constexpr int B2 = A + 1;
            if (S < 1000) {
                const int t0 = 2 * S;
                // ---- sub0: h0[t0] from hA0/hB0 (pre-read last superstep) ----
                float gr = (float)gxr[A], gz = (float)gxz[A], gn = (float)gxn[A];
                {   // refill gx set A with t0+4 (clamped, in-bounds)
                    const int tp = (t0 + 4 < T_STEPS) ? (t0 + 4) : (T_STEPS - 1);
                    const _Float16* gp = gbase + (size_t)tp * 192 + j;
                    gxr[A] = gp[0]; gxz[A] = gp[64]; gxn[A] = gp[128];
                }
                float ar = 0.f, az = 0.f, an = 0.f;
                DOT96(whr, whz, whn, hA0, hB0, ar, az, an);
                float r = sigm_f(gr + ar);
                float z = sigm_f(gz + az);
                float n = tanh_f(gn + r * (bn0h + an));
                hreg = (1.f - z) * n + z * hreg;
                h0r[A][j] = (_Float16)hreg;
                // ---- sub1: h0[t0+1]; read own fresh row (intra-wave order) ----
                U8 hA1[4], hB1[4];
                #pragma unroll
                for (int q = 0; q < 4; ++q) hA1[q].v = ((const h8*)h0r[A])[q];
                #pragma unroll
                for (int q = 0; q < 4; ++q) hB1[q].v = ((const h8*)h0r[A])[4 + q];
                float gr1 = (float)gxr[B2], gz1 = (float)gxz[B2], gn1 = (float)gxn[B2];
                {
                    const int tp = (t0 + 5 < T_STEPS) ? (t0 + 5) : (T_STEPS - 1);
                    const _Float16* gp = gbase + (size_t)tp * 192 + j;
                    gxr[B2] = gp[0]; gxz[B2] = gp[64]; gxn[B2] = gp[128];
                }
                float ar1 = 0.f, az1 = 0.f, an1 = 0.f;
                DOT96(whr, whz, whn, hA1, hB1, ar1, az1, an1);
                float r1 = sigm_f(gr1 + ar1);
                float z1 = sigm_f(gz1 + az1);
                float n1 = tanh_f(gn1 + r1 * (bn0h + an1));
                hreg = (1.f - z1) * n1 + z1 * hreg;
                h0r[B2][j] = (_Float16)hreg;
                // pre-read next superstep's sub0 source (own write, intra-wave)
                #pragma unroll
                for (int q = 0; q < 4; ++q) hA0[q].v = ((const h8*)h0r[B2])[q];
                #pragma unroll
                for (int q = 0; q < 4; ++q) hB0[q].v = ((const h8*)h0r[B2])[4 + q];
            }
            barrier_lds();
        };

        for (int si = 0; si <= 500; ++si) {
            superW0(2 * si,     IC<0>{});
            superW0(2 * si + 1, IC<2>{});
        }
        out_hidden[b * HDIM + j] = hreg;            // h0[T-1]
    } else if (w == 1) {
        // ---- wave 1: layer-1 x-side projections (lag 2) ----
        h2 xr1[32], xz1[32], xn1[32];
        {
            const float4* a4 = (const float4*)(Wih1 + (size_t)j * HDIM);
            const float4* b4 = (const float4*)(Wih1 + (size_t)(64 + j) * HDIM);
            const float4* c4 = (const float4*)(Wih1 + (size_t)(128 + j) * HDIM);
            #pragma unroll
            for (int k = 0; k < 16; ++k) {
                float4 va = a4[k], vb = b4[k], vc = c4[k];
                xr1[2*k]=mk2(va.x,va.y); xr1[2*k+1]=mk2(va.z,va.w);
                xz1[2*k]=mk2(vb.x,vb.y); xz1[2*k+1]=mk2(vb.z,vb.w);
                xn1[2*k]=mk2(vc.x,vc.y); xn1[2*k+1]=mk2(vc.z,vc.w);
            }
        }
        const float brm = bih1[j] + bhh1[j];
        const float bzm = bih1[64 + j] + bhh1[64 + j];
        const float bnx = bih1[128 + j];

        __syncthreads();

        auto superW1 = [&](int S, auto cH) {
            constexpr int H0 = decltype(cH)::v;     // (2S-2)&3 : 2 (S even) / 0 (S odd)
            constexpr int H1 = H0 + 1;
            if (S >= 1 && S <= 1000) {
                // both source rows were published by barrier S-1; issue all
                // 16 b128 up-front (row H1 latency hides under row-H0 dots)
                U8 a0[4], b0[4], a1[4], b1[4];
                #pragma unroll
                for (int q = 0; q < 4; ++q) a0[q].v = ((const h8*)h0r[H0])[q];
                #pragma unroll
                for (int q = 0; q < 4; ++q) b0[q].v = ((const h8*)h0r[H0])[4 + q];
                #pragma unroll
                for (int q = 0; q < 4; ++q) a1[q].v = ((const h8*)h0r[H1])[q];
                #pragma unroll
                for (int q = 0; q < 4; ++q) b1[q].v = ((const h8*)h0r[H1])[4 + q];
                float ar = 0.f, az = 0.f, an = 0.f;
                DOT96(xr1, xz1, xn1, a0, b0, ar, az, an);
                pxs[H0][0][j] = brm + ar;           // px[2S-2]
                pxs[H0][1][j] = bzm + az;
                pxs[H0][2][j] = bnx + an;
                float ar1 = 0.f, az1 = 0.f, an1 = 0.f;
                DOT96(xr1, xz1, xn1, a1, b1, ar1, az1, an1);
                pxs[H1][0][j] = brm + ar1;          // px[2S-1]
                pxs[H1][1][j] = bzm + az1;
                pxs[H1][2][j] = bnx + an1;
            }
            barrier_lds();
        };

        for (int si = 0; si <= 500; ++si) {
            superW1(2 * si,     IC<2>{});
            superW1(2 * si + 1, IC<0>{});
        }
    } else {
        // ---- wave 2: layer-1 recurrence + gates (lag 4) ----
        h2 hr1[32], hz1[32], hn1[32];
        {
            const float4* a4 = (const float4*)(Whh1 + (size_t)j * HDIM);
            const float4* b4 = (const float4*)(Whh1 + (size_t)(64 + j) * HDIM);
            const float4* c4 = (const float4*)(Whh1 + (size_t)(128 + j) * HDIM);
            #pragma unroll
            for (int k = 0; k < 16; ++k) {
                float4 va = a4[k], vb = b4[k], vc = c4[k];
                hr1[2*k]=mk2(va.x,va.y); hr1[2*k+1]=mk2(va.z,va.w);
                hz1[2*k]=mk2(vb.x,vb.y); hz1[2*k+1]=mk2(vb.z,vb.w);
                hn1[2*k]=mk2(vc.x,vc.y); hn1[2*k+1]=mk2(vc.z,vc.w);
            }
        }
        const float bnh = bhh1[128 + j];
        float hreg = hin[BATCH * HDIM + b * HDIM + j];
        h1r[1][j] = (_Float16)hreg;                 // h1[-1] at slot 1

        __syncthreads();

        U8 uA[4], uB[4];                            // h1[t0-1] (pre-read, own)
        #pragma unroll
        for (int q = 0; q < 4; ++q) uA[q].v = ((const h8*)h1r[1])[q];
        #pragma unroll
        for (int q = 0; q < 4; ++q) uB[q].v = ((const h8*)h1r[1])[4 + q];

        auto superW2 = [&](int S, auto cP) {
            constexpr int P0 = decltype(cP)::v;     // (2S-4)&3 : 0 (S even) / 2 (S odd)
            constexpr int P1 = P0 + 1;
            if (S >= 2) {
                // px reads issued up-front, consumed after the dot blocks
                const float pr0 = pxs[P0][0][j];
                const float pz0 = pxs[P0][1][j];
                const float pn0 = pxs[P0][2][j];
                const float pr1 = pxs[P1][0][j];
                const float pz1 = pxs[P1][1][j];
                const float pn1 = pxs[P1][2][j];
                // ---- sub0: h1[2S-4] (even index -> slot 0) ----
                float ar = 0.f, az = 0.f, an = 0.f;
                DOT96(hr1, hz1, hn1, uA, uB, ar, az, an);
                float r = sigm_f(pr0 + ar);
                float z = sigm_f(pz0 + az);
                float n = tanh_f(pn0 + r * (bnh + an));
                hreg = (1.f - z) * n + z * hreg;
                h1r[0][j] = (_Float16)hreg;
                // ---- sub1: h1[2S-3]; read own fresh row (intra-wave) ----
                U8 vA[4], vB[4];
                #pragma unroll
                for (int q = 0; q < 4; ++q) vA[q].v = ((const h8*)h1r[0])[q];
                #pragma unroll
                for (int q = 0; q < 4; ++q) vB[q].v = ((const h8*)h1r[0])[4 + q];
                float ar1 = 0.f, az1 = 0.f, an1 = 0.f;
                DOT96(hr1, hz1, hn1, vA, vB, ar1, az1, an1);
                float r1 = sigm_f(pr1 + ar1);
                float z1 = sigm_f(pz1 + az1);
                float n1 = tanh_f(pn1 + r1 * (bnh + an1));
                hreg = (1.f - z1) * n1 + z1 * hreg;
                h1r[1][j] = (_Float16)hreg;
                // pre-read next superstep's sub0 source (own write)
                #pragma unroll
                for (int q = 0; q < 4; ++q) uA[q].v = ((const h8*)h1r[1])[q];
                #pragma unroll
                for (int q = 0; q < 4; ++q) uB[q].v = ((const h8*)h1r[1])[4 + q];
            }
            barrier_lds();
        };

        for (int si = 0; si <= 500; ++si) {
            superW2(2 * si,     IC<0>{});
            superW2(2 * si + 1, IC<2>{});
        }
        out_hidden[BATCH * HDIM + b * HDIM + j] = hreg;   // h1[T-1]
    }
}

// logits[b][o] = b_fc[o] + sum_j relu(h1T[b][j]) * W_fc[o][j]
__global__ void fc_kernel(const float* __restrict__ hidden,   // [2,B,H] region
                          const float* __restrict__ Wfc,      // [29,64]
                          const float* __restrict__ bfc,      // [29]
                          float* __restrict__ logits)         // [B,29]
{
    const int b = blockIdx.x;
    const int o = threadIdx.x;
    if (o < 29) {
        const float* hb = hidden + BATCH * HDIM + b * HDIM;   // h1T
        float acc = bfc[o];
        #pragma unroll
        for (int j = 0; j < HDIM; ++j)
            acc += fmaxf(hb[j], 0.f) * Wfc[o * HDIM + j];
        logits[b * 29 + o] = acc;
    }
}

extern "C" void kernel_launch(void* const* d_in, const int* in_sizes, int n_in,
                              void* d_out, int out_size, void* d_ws, size_t ws_size,
                              hipStream_t stream) {
    const float* x    = (const float*)d_in[0];
    const float* h    = (const float*)d_in[1];
    const float* Wih0 = (const float*)d_in[2];
    const float* Whh0 = (const float*)d_in[3];
    const float* bih0 = (const float*)d_in[4];
    const float* bhh0 = (const float*)d_in[5];
    const float* Wih1 = (const float*)d_in[6];
    const float* Whh1 = (const float*)d_in[7];
    const float* bih1 = (const float*)d_in[8];
    const float* bhh1 = (const float*)d_in[9];
    const float* Wfc  = (const float*)d_in[10];
    const float* bfc  = (const float*)d_in[11];

    float* out    = (float*)d_out;
    float* logits = out;                      // [256,29]
    float* hidden = out + BATCH * 29;         // [2,256,64]

    // Workspace: gx fp16 [B*T][192] = 196,608,000 B. All accesses in-bounds
    // (scan-side prefetch row clamped to T_STEPS-1).
    _Float16* gxp = (_Float16*)d_ws;

    gx_gemm<<<4096, 64, 0, stream>>>(x, Wih0, bih0, bhh0, gxp);
    gru_scan<<<BATCH, 192, 0, stream>>>(
        gxp, h, Whh0, bhh0, Wih1, Whh1, bih1, bhh1, hidden);
    fc_kernel<<<BATCH, 64, 0, stream>>>(hidden, Wfc, bfc, logits);
}

// Round 8
// 1107.202 us; speedup vs baseline: 1.1675x; 1.0863x over previous
//
#include <hip/hip_runtime.h>

#define T_STEPS 2000
#define BATCH   256
#define F_IN    80
#define HDIM    64

template<int N> struct IC { static constexpr int v = N; };

typedef _Float16 h2 __attribute__((ext_vector_type(2)));
typedef _Float16 h8 __attribute__((ext_vector_type(8)));

union U8 { h8 v; h2 p[4]; };

// ---- fast transcendentals (fp32; logits threshold 1.77e-2) ----
__device__ __forceinline__ float sigm_f(float v) {
    float e = __expf(-v);
    return __builtin_amdgcn_rcpf(1.f + e);
}
__device__ __forceinline__ float tanh_f(float v) {
    v = fminf(fmaxf(v, -15.f), 15.f);
    float e = __expf(-2.f * v);
    return (1.f - e) * __builtin_amdgcn_rcpf(1.f + e);
}
// LDS-only barrier: drains LDS ops (lgkmcnt=0) but leaves global loads in
// flight (vmcnt=63). Proven safe in rounds 3/4/6/7.
__device__ __forceinline__ void barrier_lds() {
    __builtin_amdgcn_s_waitcnt(0xC07F);   // vmcnt=63, expcnt=7, lgkmcnt=0
    __builtin_amdgcn_s_barrier();
}
// v_dot2_f32_f16: 2 fp16 MACs, fp32 accumulate, full-rate (~2 cyc issue).
__device__ __forceinline__ float fdot2(h2 a, h2 b, float c) {
    return __builtin_amdgcn_fdot2(a, b, c, false);
}
__device__ __forceinline__ h2 mk2(float a, float b) {
    h2 r; r.x = (_Float16)a; r.y = (_Float16)b; return r;
}

// 96 dot2 as SIX interleaved 16-deep chains (A/B half-K per gate).
// Same-chain ops are 12 issue-cycles apart -> dep latency fully covered.
#define DOT96_6(WR, WZ, WN, HA, HB, ARA, ARB, AZA, AZB, ANA, ANB)   \
    {                                                                \
        _Pragma("unroll")                                            \
        for (int q = 0; q < 4; ++q) {                                \
            _Pragma("unroll")                                        \
            for (int pp = 0; pp < 4; ++pp) {                         \
                ARA = fdot2(WR[4*q+pp],    HA[q].p[pp], ARA);        \
                ARB = fdot2(WR[16+4*q+pp], HB[q].p[pp], ARB);        \
                AZA = fdot2(WZ[4*q+pp],    HA[q].p[pp], AZA);        \
                AZB = fdot2(WZ[16+4*q+pp], HB[q].p[pp], AZB);        \
                ANA = fdot2(WN[4*q+pp],    HA[q].p[pp], ANA);        \
                ANB = fdot2(WN[16+4*q+pp], HB[q].p[pp], ANB);        \
            }                                                        \
        }                                                            \
    }

// ---------------------------------------------------------------------------
// gx GEMM: gx[r,c] = bias(c) + Wih0[c,:] . x[r,:], fp16 out, biases folded.
// TWO rows per iteration: 6 independent dot chains, one LDS-read wait per 2
// rows, weights reused from registers across both rows. 4-slot LDS ring +
// distance-4 register prefetch; single wave per block, intra-wave ordering
// only (slots written/read this iter are disjoint).
// ---------------------------------------------------------------------------
__global__ __launch_bounds__(64, 2)
void gx_gemm(const float* __restrict__ x,        // [B*T, 80] fp32
             const float* __restrict__ Wih0,     // [192, 80] fp32
             const float* __restrict__ bih0,
             const float* __restrict__ bhh0,
             _Float16* __restrict__ gxp)         // [B*T, 192] fp16
{
    const int j = threadIdx.x;                   // 0..63
    const long total = (long)BATCH * T_STEPS;
    const long per   = total / gridDim.x;        // 125
    const long r0    = (long)blockIdx.x * per;
    const long r1    = r0 + per;

    h2 wr[40], wz[40], wn[40];
    {
        const float4* a4 = (const float4*)(Wih0 + (size_t)j * F_IN);
        const float4* b4 = (const float4*)(Wih0 + (size_t)(64 + j) * F_IN);
        const float4* c4 = (const float4*)(Wih0 + (size_t)(128 + j) * F_IN);
        #pragma unroll
        for (int k = 0; k < 20; ++k) {
            float4 va = a4[k], vb = b4[k], vc = c4[k];
            wr[2*k] = mk2(va.x, va.y); wr[2*k+1] = mk2(va.z, va.w);
            wz[2*k] = mk2(vb.x, vb.y); wz[2*k+1] = mk2(vb.z, vb.w);
            wn[2*k] = mk2(vc.x, vc.y); wn[2*k+1] = mk2(vc.z, vc.w);
        }
    }
    const float br = bih0[j]       + bhh0[j];
    const float bz = bih0[64 + j]  + bhh0[64 + j];
    const float bn = bih0[128 + j];

    __shared__ __align__(16) _Float16 xs[4][80]; // slot = (r - r0) & 3

    const bool ld = (j < 40);
    // prologue: stage rows r0, r0+1; prefetch r0+2, r0+3 into registers
    if (ld) {
        float2 v0 = ((const float2*)(x + r0 * F_IN))[j];
        float2 v1 = ((const float2*)(x + (r0 + 1) * F_IN))[j];
        *(h2*)&xs[0][2 * j] = mk2(v0.x, v0.y);
        *(h2*)&xs[1][2 * j] = mk2(v1.x, v1.y);
    }
    float2 vA = make_float2(0.f, 0.f), vB = make_float2(0.f, 0.f);
    if (ld && r0 + 2 < r1) vA = ((const float2*)(x + (r0 + 2) * F_IN))[j];
    if (ld && r0 + 3 < r1) vB = ((const float2*)(x + (r0 + 3) * F_IN))[j];

    long r = r0;
    for (; r + 1 < r1; r += 2) {
        // distance-4 prefetch (in flight across this pair's compute)
        float2 v4 = make_float2(0.f, 0.f), v5 = make_float2(0.f, 0.f);
        if (ld && r + 4 < r1) v4 = ((const float2*)(x + (r + 4) * F_IN))[j];
        if (ld && r + 5 < r1) v5 = ((const float2*)(x + (r + 5) * F_IN))[j];

        const int s0 = (int)(r - r0) & 3, s1 = (s0 + 1) & 3;
        U8 x0[10], x1[10];
        #pragma unroll
        for (int q = 0; q < 10; ++q) {
            x0[q].v = ((const h8*)xs[s0])[q];
            x1[q].v = ((const h8*)xs[s1])[q];
        }
        // stage rows r+2, r+3 into the other two slots (disjoint from reads;
        // data loaded one pair ago, vmcnt long satisfied)
        if (ld && r + 2 < r1) *(h2*)&xs[(s0 + 2) & 3][2 * j] = mk2(vA.x, vA.y);
        if (ld && r + 3 < r1) *(h2*)&xs[(s0 + 3) & 3][2 * j] = mk2(vB.x, vB.y);
        vA = v4; vB = v5;

        float ar0 = br, az0 = bz, an0 = bn;
        float ar1 = br, az1 = bz, an1 = bn;
        #pragma unroll
        for (int q = 0; q < 10; ++q)
            #pragma unroll
            for (int pp = 0; pp < 4; ++pp) {
                ar0 = fdot2(wr[4*q+pp], x0[q].p[pp], ar0);
                ar1 = fdot2(wr[4*q+pp], x1[q].p[pp], ar1);
                az0 = fdot2(wz[4*q+pp], x0[q].p[pp], az0);
                az1 = fdot2(wz[4*q+pp], x1[q].p[pp], az1);
                an0 = fdot2(wn[4*q+pp], x0[q].p[pp], an0);
                an1 = fdot2(wn[4*q+pp], x1[q].p[pp], an1);
            }
        _Float16* g0 = gxp + r * 192;
        _Float16* g1 = gxp + (r + 1) * 192;
        g0[j]       = (_Float16)ar0;
        g0[64 + j]  = (_Float16)az0;
        g0[128 + j] = (_Float16)an0;
        g1[j]       = (_Float16)ar1;
        g1[64 + j]  = (_Float16)az1;
        g1[128 + j] = (_Float16)an1;
    }
    if (r < r1) {   // odd tail row (already staged two iterations ago)
        const int s0 = (int)(r - r0) & 3;
        U8 x0[10];
        #pragma unroll
        for (int q = 0; q < 10; ++q) x0[q].v = ((const h8*)xs[s0])[q];
        float ar0 = br, az0 = bz, an0 = bn;
        #pragma unroll
        for (int q = 0; q < 10; ++q)
            #pragma unroll
            for (int pp = 0; pp < 4; ++pp) {
                ar0 = fdot2(wr[4*q+pp], x0[q].p[pp], ar0);
                az0 = fdot2(wz[4*q+pp], x0[q].p[pp], az0);
                an0 = fdot2(wn[4*q+pp], x0[q].p[pp], an0);
            }
        _Float16* g0 = gxp + r * 192;
        g0[j]       = (_Float16)ar0;
        g0[64 + j]  = (_Float16)az0;
        g0[128 + j] = (_Float16)an0;
    }
}

// ---------------------------------------------------------------------------
// Fused 2-layer GRU scan — R3-proven structure (best measured: 787 us):
// 3 waves, one barrier/step, dot2 math, reads at top of body. Only change:
// each 96-dot block now runs as SIX interleaved 16-deep chains (DOT96_6)
// to eliminate accumulator dependency stalls.
//   w0 @ step i : h0[i]   = GRU(gx[i], Whh0 . h0[i-1])
//   w1 @ step i : px[i-1] = bias + Wih1 . h0[i-1]
//   w2 @ step i : h1[i-2] = GRU(px[i-2], Whh1 . h1[i-3])
// ---------------------------------------------------------------------------
__global__ __launch_bounds__(192, 1)
void gru_scan(const _Float16* __restrict__ gx,   // [B*T, 192] fp16 (bias-folded)
              const float* __restrict__ hin,     // [2,B,H]
              const float* __restrict__ Whh0,    // [192,64]
              const float* __restrict__ bhh0,
              const float* __restrict__ Wih1,    // [192,64]
              const float* __restrict__ Whh1,    // [192,64]
              const float* __restrict__ bih1, const float* __restrict__ bhh1,
              float* __restrict__ out_hidden)    // [2,B,H] region of d_out
{
    const int b = blockIdx.x;
    const int j = threadIdx.x & 63;
    const int w = threadIdx.x >> 6;

    __shared__ __align__(16) _Float16 h0r[4][64];   // ring: slot i&3 = h0[i]
    __shared__ __align__(16) _Float16 h1r[2][64];   // ping-pong: slot t&1 = h1[t]
    __shared__ __align__(16) float    pxs[2][3][64];// ping-pong: slot t&1 = px[t]

    if (w == 0) {
        // ---- wave 0: layer-0 recurrence ----
        h2 whr[32], whz[32], whn[32];
        {
            const float4* a4 = (const float4*)(Whh0 + (size_t)j * HDIM);
            const float4* b4 = (const float4*)(Whh0 + (size_t)(64 + j) * HDIM);
            const float4* c4 = (const float4*)(Whh0 + (size_t)(128 + j) * HDIM);
            #pragma unroll
            for (int k = 0; k < 16; ++k) {
                float4 va = a4[k], vb = b4[k], vc = c4[k];
                whr[2*k]=mk2(va.x,va.y); whr[2*k+1]=mk2(va.z,va.w);
                whz[2*k]=mk2(vb.x,vb.y); whz[2*k+1]=mk2(vb.z,vb.w);
                whn[2*k]=mk2(vc.x,vc.y); whn[2*k+1]=mk2(vc.z,vc.w);
            }
        }
        const float bn0h = bhh0[128 + j];
        float hreg = hin[b * HDIM + j];
        h0r[3][j] = (_Float16)hreg;                 // h0[-1] at slot 3

        const _Float16* gbase = gx + (size_t)b * T_STEPS * 192;
        _Float16 grf[2], gzf[2], gnf[2];            // depth-2 gx prefetch
        grf[0] = gbase[j];       gzf[0] = gbase[64 + j];       gnf[0] = gbase[128 + j];
        grf[1] = gbase[192 + j]; gzf[1] = gbase[192 + 64 + j]; gnf[1] = gbase[192 + 128 + j];

        __syncthreads();

        auto stepL0 = [&](int i, auto c3) {
            constexpr int I3 = decltype(c3)::v;     // i&3
            constexpr int IP = I3 & 1;
            constexpr int IR = (I3 + 3) & 3;        // (i-1)&3
            // top-of-body reads, A/B interleaved so both halves arrive early
            U8 hA[4], hB[4];
            #pragma unroll
            for (int q = 0; q < 4; ++q) {
                hA[q].v = ((const h8*)h0r[IR])[q];
                hB[q].v = ((const h8*)h0r[IR])[4 + q];
            }
            // gx cvt + next prefetch hide the ds_read latency
            float gr = (float)grf[IP];
            float gz = (float)gzf[IP];
            float gn = (float)gnf[IP];
            const int ipf = (i + 2 < T_STEPS) ? (i + 2) : (T_STEPS - 1);  // in-bounds
            const _Float16* gnx = gbase + (size_t)ipf * 192 + j;
            grf[IP] = gnx[0]; gzf[IP] = gnx[64]; gnf[IP] = gnx[128];

            float arA = 0.f, arB = 0.f, azA = 0.f, azB = 0.f, anA = 0.f, anB = 0.f;
            DOT96_6(whr, whz, whn, hA, hB, arA, arB, azA, azB, anA, anB);
            float r = sigm_f(gr + (arA + arB));
            float z = sigm_f(gz + (azA + azB));
            float n = tanh_f(gn + r * (bn0h + (anA + anB)));
            hreg = (1.f - z) * n + z * hreg;
            h0r[I3][j] = (_Float16)hreg;            // one ds_write_b16
            barrier_lds();                          // drain = write only (cheap)
        };

        for (int ii = 0; ii < T_STEPS / 4; ++ii) {
            const int i = 4 * ii;
            stepL0(i + 0, IC<0>{}); stepL0(i + 1, IC<1>{});
            stepL0(i + 2, IC<2>{}); stepL0(i + 3, IC<3>{});
        }
        barrier_lds();                              // epilogue (match w1/w2)
        out_hidden[b * HDIM + j] = hreg;            // h0[T-1]
    } else if (w == 1) {
        // ---- wave 1: layer-1 x-side projections ----
        h2 xr1[32], xz1[32], xn1[32];
        {
            const float4* a4 = (const float4*)(Wih1 + (size_t)j * HDIM);
            const float4* b4 = (const float4*)(Wih1 + (size_t)(64 + j) * HDIM);
            const float4* c4 = (const float4*)(Wih1 + (size_t)(128 + j) * HDIM);
            #pragma unroll
            for (int k = 0; k < 16; ++k) {
                float4 va = a4[k], vb = b4[k], vc = c4[k];
                xr1[2*k]=mk2(va.x,va.y); xr1[2*k+1]=mk2(va.z,va.w);
                xz1[2*k]=mk2(vb.x,vb.y); xz1[2*k+1]=mk2(vb.z,vb.w);
                xn1[2*k]=mk2(vc.x,vc.y); xn1[2*k+1]=mk2(vc.z,vc.w);
            }
        }
        const float brm = bih1[j] + bhh1[j];
        const float bzm = bih1[64 + j] + bhh1[64 + j];
        const float bnx = bih1[128 + j];

        __syncthreads();

        auto stepW1 = [&](auto c3) {   // at step i: px[i-1] = bias + Wih1.h0[i-1]
            constexpr int I3 = decltype(c3)::v;     // i&3
            constexpr int IR = (I3 + 3) & 3;        // (i-1)&3
            constexpr int PS = (I3 + 1) & 1;        // (i-1)&1
            U8 hA[4], hB[4];
            #pragma unroll
            for (int q = 0; q < 4; ++q) {
                hA[q].v = ((const h8*)h0r[IR])[q];
                hB[q].v = ((const h8*)h0r[IR])[4 + q];
            }
            float arA = 0.f, arB = 0.f, azA = 0.f, azB = 0.f, anA = 0.f, anB = 0.f;
            DOT96_6(xr1, xz1, xn1, hA, hB, arA, arB, azA, azB, anA, anB);
            pxs[PS][0][j] = brm + (arA + arB);      // 3 ds_write_b32
            pxs[PS][1][j] = bzm + (azA + azB);
            pxs[PS][2][j] = bnx + (anA + anB);
            barrier_lds();
        };

        barrier_lds();                              // i = 0 (idle)
        stepW1(IC<1>{}); stepW1(IC<2>{}); stepW1(IC<3>{});
        for (int ii = 1; ii < T_STEPS / 4; ++ii) {
            stepW1(IC<0>{}); stepW1(IC<1>{});
            stepW1(IC<2>{}); stepW1(IC<3>{});
        }
        stepW1(IC<0>{});                            // epilogue: px[T-1]
    } else {
        // ---- wave 2: layer-1 recurrence + gates ----
        h2 hr1[32], hz1[32], hn1[32];
        {
            const float4* a4 = (const float4*)(Whh1 + (size_t)j * HDIM);
            const float4* b4 = (const float4*)(Whh1 + (size_t)(64 + j) * HDIM);
            const float4* c4 = (const float4*)(Whh1 + (size_t)(128 + j) * HDIM);
            #pragma unroll
            for (int k = 0; k < 16; ++k) {
                float4 va = a4[k], vb = b4[k], vc = c4[k];
                hr1[2*k]=mk2(va.x,va.y); hr1[2*k+1]=mk2(va.z,va.w);
                hz1[2*k]=mk2(vb.x,vb.y); hz1[2*k+1]=mk2(vb.z,vb.w);
                hn1[2*k]=mk2(vc.x,vc.y); hn1[2*k+1]=mk2(vc.z,vc.w);
            }
        }
        const float bnh = bhh1[128 + j];
        float hreg = hin[BATCH * HDIM + b * HDIM + j];
        h1r[1][j] = (_Float16)hreg;                 // h1[-1] at slot 1

        __syncthreads();

        auto stepW2 = [&](auto c3) {   // at step i: t = i-2
            constexpr int I3 = decltype(c3)::v;     // i&3
            constexpr int IP = I3 & 1;              // t&1 == i&1
            constexpr int IU = IP ^ 1;              // (i-3)&1 = slot of h1[i-3]
            // top-of-body reads: px[i-2] + h1[i-3]
            const float pr = pxs[IP][0][j];
            const float pz = pxs[IP][1][j];
            const float pn = pxs[IP][2][j];
            U8 hA[4], hB[4];
            #pragma unroll
            for (int q = 0; q < 4; ++q) {
                hA[q].v = ((const h8*)h1r[IU])[q];
                hB[q].v = ((const h8*)h1r[IU])[4 + q];
            }
            float arA = 0.f, arB = 0.f, azA = 0.f, azB = 0.f, anA = 0.f, anB = 0.f;
            DOT96_6(hr1, hz1, hn1, hA, hB, arA, arB, azA, azB, anA, anB);
            float r = sigm_f(pr + (arA + arB));
            float z = sigm_f(pz + (azA + azB));
            float n = tanh_f(pn + r * (bnh + (anA + anB)));
            hreg = (1.f - z) * n + z * hreg;
            h1r[IP][j] = (_Float16)hreg;            // h1[i-2]
            barrier_lds();
        };

        barrier_lds(); barrier_lds();               // i = 0, 1 (idle)
        stepW2(IC<2>{}); stepW2(IC<3>{});
        for (int ii = 1; ii < T_STEPS / 4; ++ii) {
            stepW2(IC<0>{}); stepW2(IC<1>{});
            stepW2(IC<2>{}); stepW2(IC<3>{});
        }
        stepW2(IC<0>{});                            // epilogue: t = T-2
        {   // tail: t = T-1 (no barrier; px[T-1] in pxs[1], h1[T-2] in h1r[0])
            const float pr = pxs[1][0][j];
            const float pz = pxs[1][1][j];
            const float pn = pxs[1][2][j];
            U8 hA[4], hB[4];
            #pragma unroll
            for (int q = 0; q < 4; ++q) {
                hA[q].v = ((const h8*)h1r[0])[q];
                hB[q].v = ((const h8*)h1r[0])[4 + q];
            }
            float arA = 0.f, arB = 0.f, azA = 0.f, azB = 0.f, anA = 0.f, anB = 0.f;
            DOT96_6(hr1, hz1, hn1, hA, hB, arA, arB, azA, azB, anA, anB);
            float r = sigm_f(pr + (arA + arB));
            float z = sigm_f(pz + (azA + azB));
            float n = tanh_f(pn + r * (bnh + (anA + anB)));
            hreg = (1.f - z) * n + z * hreg;
        }
        out_hidden[BATCH * HDIM + b * HDIM + j] = hreg;   // h1[T-1]
    }
}

// logits[b][o] = b_fc[o] + sum_j relu(h1T[b][j]) * W_fc[o][j]
__global__ void fc_kernel(const float* __restrict__ hidden,   // [2,B,H] region
                          const float* __restrict__ Wfc,      // [29,64]
                          const float* __restrict__ bfc,      // [29]
                          float* __restrict__ logits)         // [B,29]
{
    const int b = blockIdx.x;
    const int o = threadIdx.x;
    if (o < 29) {
        const float* hb = hidden + BATCH * HDIM + b * HDIM;   // h1T
        float acc = bfc[o];
        #pragma unroll
        for (int j = 0; j < HDIM; ++j)
            acc += fmaxf(hb[j], 0.f) * Wfc[o * HDIM + j];
        logits[b * 29 + o] = acc;
    }
}

extern "C" void kernel_launch(void* const* d_in, const int* in_sizes, int n_in,
                              void* d_out, int out_size, void* d_ws, size_t ws_size,
                              hipStream_t stream) {
    const float* x    = (const float*)d_in[0];
    const float* h    = (const float*)d_in[1];
    const float* Wih0 = (const float*)d_in[2];
    const float* Whh0 = (const float*)d_in[3];
    const float* bih0 = (const float*)d_in[4];
    const float* bhh0 = (const float*)d_in[5];
    const float* Wih1 = (const float*)d_in[6];
    const float* Whh1 = (const float*)d_in[7];
    const float* bih1 = (const float*)d_in[8];
    const float* bhh1 = (const float*)d_in[9];
    const float* Wfc  = (const float*)d_in[10];
    const float* bfc  = (const float*)d_in[11];

    float* out    = (float*)d_out;
    float* logits = out;                      // [256,29]
    float* hidden = out + BATCH * 29;         // [2,256,64]

    // Workspace: gx fp16 [B*T][192] = 196,608,000 B. All accesses in-bounds
    // (scan-side prefetch row clamped to T_STEPS-1).
    _Float16* gxp = (_Float16*)d_ws;

    gx_gemm<<<4096, 64, 0, stream>>>(x, Wih0, bih0, bhh0, gxp);
    gru_scan<<<BATCH, 192, 0, stream>>>(
        gxp, h, Whh0, bhh0, Wih1, Whh1, bih1, bhh1, hidden);
    fc_kernel<<<BATCH, 64, 0, stream>>>(hidden, Wfc, bfc, logits);
}